// Round 1
// baseline (1040.260 us; speedup 1.0000x reference)
//
#include <hip/hip_runtime.h>
#include <hip/hip_bf16.h>

// SwinMLP block, fp32 in/out, bf16 MFMA internals.
// Pipeline:
//   1) cvt_t: w1 -> w1t (bf16, N x K), w2 -> w2t (bf16, N x K)
//   2) fused_pre: per-row LN1 + per-head 32x32 spatial matmul + residual -> x2 (fp32, stored in d_out)
//      + LN2(x2) -> y (bf16, ws)
//   3) gemm_bt<512,2048,GELU>: z = gelu(y @ w1 + b1)  (bf16, ws)
//   4) gemm_bt<2048,512,RES>:  d_out = x2 + z @ w2 + b2 (in-place residual on d_out)

typedef __bf16 bf16x8 __attribute__((ext_vector_type(8)));
typedef float f32x4 __attribute__((ext_vector_type(4)));

constexpr int CDIM = 512;
constexpr int HID = 2048;
constexpr int MROWS = 32 * 3136;  // 100352 = 784 * 128
constexpr float LN_EPS = 1e-5f;

static __device__ __forceinline__ float gelu_tanh(float x) {
  // 0.5*x*(1+tanh(sqrt(2/pi)*(x+0.044715 x^3))), tanh via exp (overflow-safe)
  const float u = 0.7978845608028654f * fmaf(0.044715f * x * x, x, x);
  const float e = __expf(2.0f * u);
  return 0.5f * x * (2.0f - 2.0f / (e + 1.0f));
}

static __device__ __forceinline__ void load_lds16(const void* g, void* l) {
  // 16B per lane, LDS dest = wave-uniform base + lane*16 (linear)
  __builtin_amdgcn_global_load_lds((__attribute__((address_space(1))) void*)g,
                                   (__attribute__((address_space(3))) void*)l,
                                   16, 0, 0);
}

// ---------------- weight transpose + bf16 convert ----------------
// dst[n*KD + k] = src[k*ND + n]
template <int KD>
__global__ __launch_bounds__(256) void cvt_t(const float* __restrict__ src,
                                             __hip_bfloat16* __restrict__ dst,
                                             int ND) {
  const int i = blockIdx.x * 256 + threadIdx.x;
  const int n = i / KD;
  const int k = i - n * KD;
  dst[i] = __float2bfloat16(src[(size_t)k * ND + n]);
}

// ---------------- fused LN1 + spatial mix + residual + LN2 ----------------
__global__ __launch_bounds__(256) void fused_pre(
    const float* __restrict__ x, const float* __restrict__ g1,
    const float* __restrict__ b1, const float* __restrict__ wsp,
    const float* __restrict__ g2, const float* __restrict__ b2,
    float* __restrict__ x2out, __hip_bfloat16* __restrict__ yout) {
  __shared__ float lnbuf[CDIM];
  __shared__ float red[8];

  const int t = threadIdx.x;
  const int lane = t & 63;
  const int w = t >> 6;
  const int c0 = t, c1 = t + 256;
  const int hd0 = c0 >> 5, e0 = c0 & 31;
  const int hd1 = c1 >> 5, e1 = c1 & 31;

  // per-thread spatial-mix weight columns (fixed across rows)
  float wc0[32], wc1[32];
#pragma unroll
  for (int d = 0; d < 32; ++d) {
    wc0[d] = wsp[(hd0 * 32 + d) * 32 + e0];
    wc1[d] = wsp[(hd1 * 32 + d) * 32 + e1];
  }
  const float g1v0 = g1[c0], g1v1 = g1[c1], b1v0 = b1[c0], b1v1 = b1[c1];
  const float g2v0 = g2[c0], g2v1 = g2[c1], b2v0 = b2[c0], b2v1 = b2[c1];

  for (int r = blockIdx.x; r < MROWS; r += gridDim.x) {
    const float* xr = x + (size_t)r * CDIM;
    const float xv0 = xr[c0], xv1 = xr[c1];

    // LN1 stats
    float s = xv0 + xv1, ss = xv0 * xv0 + xv1 * xv1;
#pragma unroll
    for (int off = 32; off; off >>= 1) {
      s += __shfl_down(s, off);
      ss += __shfl_down(ss, off);
    }
    if (lane == 0) { red[w * 2] = s; red[w * 2 + 1] = ss; }
    __syncthreads();  // B1
    s = red[0] + red[2] + red[4] + red[6];
    ss = red[1] + red[3] + red[5] + red[7];
    float mu = s * (1.0f / CDIM);
    float var = ss * (1.0f / CDIM) - mu * mu;
    float rs = rsqrtf(var + LN_EPS);
    lnbuf[c0] = (xv0 - mu) * rs * g1v0 + b1v0;
    lnbuf[c1] = (xv1 - mu) * rs * g1v1 + b1v1;
    __syncthreads();  // B2

    // per-head 32x32 matmul (2-way LDS broadcast per wave: conflict-free)
    float h0 = 0.f, h1 = 0.f;
#pragma unroll
    for (int d = 0; d < 32; ++d) {
      h0 = fmaf(lnbuf[hd0 * 32 + d], wc0[d], h0);
      h1 = fmaf(lnbuf[hd1 * 32 + d], wc1[d], h1);
    }
    const float a0 = xv0 + h0, a1 = xv1 + h1;
    x2out[(size_t)r * CDIM + c0] = a0;
    x2out[(size_t)r * CDIM + c1] = a1;

    // LN2 stats
    s = a0 + a1;
    ss = a0 * a0 + a1 * a1;
#pragma unroll
    for (int off = 32; off; off >>= 1) {
      s += __shfl_down(s, off);
      ss += __shfl_down(ss, off);
    }
    if (lane == 0) { red[w * 2] = s; red[w * 2 + 1] = ss; }
    __syncthreads();  // B3
    s = red[0] + red[2] + red[4] + red[6];
    ss = red[1] + red[3] + red[5] + red[7];
    mu = s * (1.0f / CDIM);
    var = ss * (1.0f / CDIM) - mu * mu;
    rs = rsqrtf(var + LN_EPS);
    yout[(size_t)r * CDIM + c0] = __float2bfloat16((a0 - mu) * rs * g2v0 + b2v0);
    yout[(size_t)r * CDIM + c1] = __float2bfloat16((a1 - mu) * rs * g2v1 + b2v1);
    __syncthreads();  // B4 (lnbuf/red reuse next row)
  }
}

// ---------------- bf16 MFMA GEMM: C(MxN) = A(MxK) * Bt(NxK)^T ----------------
// m97 structure: 128x128 tile, 4 waves (2x2 of 64x64), BK=32, global_load_lds w16,
// 2 barriers per K-step. GELU=true: zout=bf16 gelu(acc+bias). else: fout += acc+bias.
template <int K, int N, bool GELU>
__global__ __launch_bounds__(256) void gemm_bt(
    const __hip_bfloat16* __restrict__ A, const __hip_bfloat16* __restrict__ Bt,
    const float* __restrict__ bias, __hip_bfloat16* __restrict__ zout,
    float* __restrict__ fout) {
  constexpr int NT = N / 128;
  __shared__ __attribute__((aligned(16))) __hip_bfloat16 As[128 * 32];
  __shared__ __attribute__((aligned(16))) __hip_bfloat16 Bs[128 * 32];

  const int tid = threadIdx.x;
  const int lane = tid & 63;
  const int w = tid >> 6;
  const int wr = w >> 1, wc = w & 1;
  const int bid = blockIdx.x;
  const int tm = bid / NT;         // consecutive bids share the A panel (L2 reuse)
  const int tn = bid - tm * NT;
  const size_t am0 = (size_t)tm * 128;
  const int bn0 = tn * 128;

  // staging: segment s in [0,512) of 16B; rows = s>>2, k-sub = (s&3)*8
  const int s0 = w * 64 + lane;
  const int r0 = s0 >> 2, k0 = (s0 & 3) * 8;
  const int s1 = s0 + 256;
  const int r1 = s1 >> 2, k1 = (s1 & 3) * 8;
  const __hip_bfloat16* a0p = A + (am0 + r0) * K + k0;
  const __hip_bfloat16* a1p = A + (am0 + r1) * K + k1;
  const __hip_bfloat16* b0p = Bt + (size_t)(bn0 + r0) * K + k0;
  const __hip_bfloat16* b1p = Bt + (size_t)(bn0 + r1) * K + k1;
  __hip_bfloat16* lA0 = As + (size_t)(w * 64) * 8;
  __hip_bfloat16* lA1 = As + (size_t)(w * 64 + 256) * 8;
  __hip_bfloat16* lB0 = Bs + (size_t)(w * 64) * 8;
  __hip_bfloat16* lB1 = Bs + (size_t)(w * 64 + 256) * 8;

  f32x4 acc[4][4] = {};
  const int fr = lane & 15;
  const int kg = (lane >> 4) * 8;

  for (int kt = 0; kt < K / 32; ++kt) {
    const int kb = kt * 32;
    load_lds16(a0p + kb, lA0);
    load_lds16(a1p + kb, lA1);
    load_lds16(b0p + kb, lB0);
    load_lds16(b1p + kb, lB1);
    __syncthreads();  // drains vmcnt(0) then barrier

    bf16x8 af[4], bfv[4];
#pragma unroll
    for (int m = 0; m < 4; ++m)
      af[m] = *(const bf16x8*)(As + (wr * 64 + m * 16 + fr) * 32 + kg);
#pragma unroll
    for (int n = 0; n < 4; ++n)
      bfv[n] = *(const bf16x8*)(Bs + (wc * 64 + n * 16 + fr) * 32 + kg);
#pragma unroll
    for (int m = 0; m < 4; ++m)
#pragma unroll
      for (int n = 0; n < 4; ++n)
        acc[m][n] = __builtin_amdgcn_mfma_f32_16x16x32_bf16(af[m], bfv[n],
                                                            acc[m][n], 0, 0, 0);
    __syncthreads();  // LDS reads done before next stage
  }

  // epilogue: C/D mapping col = lane&15, row = (lane>>4)*4 + j  [m89/m91-verified]
  const int cr = (lane >> 4) * 4;
  const int cc = lane & 15;
#pragma unroll
  for (int n = 0; n < 4; ++n) {
    const int col = bn0 + wc * 64 + n * 16 + cc;
    const float bv = bias[col];
#pragma unroll
    for (int m = 0; m < 4; ++m) {
      const size_t row = am0 + wr * 64 + m * 16 + cr;
#pragma unroll
      for (int j = 0; j < 4; ++j) {
        const float v = acc[m][n][j] + bv;
        const size_t off = (row + j) * N + col;
        if constexpr (GELU) {
          zout[off] = __float2bfloat16(gelu_tanh(v));
        } else {
          fout[off] = fout[off] + v;  // += x2 residual (in-place on d_out)
        }
      }
    }
  }
}

extern "C" void kernel_launch(void* const* d_in, const int* in_sizes, int n_in,
                              void* d_out, int out_size, void* d_ws,
                              size_t ws_size, hipStream_t stream) {
  const float* x = (const float*)d_in[0];
  const float* n1g = (const float*)d_in[1];
  const float* n1b = (const float*)d_in[2];
  const float* wsp = (const float*)d_in[3];
  const float* n2g = (const float*)d_in[4];
  const float* n2b = (const float*)d_in[5];
  const float* w1 = (const float*)d_in[6];
  const float* b1 = (const float*)d_in[7];
  const float* w2 = (const float*)d_in[8];
  const float* b2 = (const float*)d_in[9];
  float* out = (float*)d_out;

  // ws layout (bf16): y[M*512] | z[M*2048] | w1t[2048*512] | w2t[512*2048]
  // total = 518 MB
  __hip_bfloat16* ybuf = (__hip_bfloat16*)d_ws;
  __hip_bfloat16* zbuf = ybuf + (size_t)MROWS * CDIM;
  __hip_bfloat16* w1t = zbuf + (size_t)MROWS * HID;
  __hip_bfloat16* w2t = w1t + (size_t)CDIM * HID;

  cvt_t<CDIM><<<(CDIM * HID) / 256, 256, 0, stream>>>(w1, w1t, HID);
  cvt_t<HID><<<(CDIM * HID) / 256, 256, 0, stream>>>(w2, w2t, CDIM);
  fused_pre<<<2048, 256, 0, stream>>>(x, n1g, n1b, wsp, n2g, n2b, out, ybuf);
  gemm_bt<CDIM, HID, true><<<(MROWS / 128) * (HID / 128), 256, 0, stream>>>(
      ybuf, w1t, b1, zbuf, nullptr);
  gemm_bt<HID, CDIM, false><<<(MROWS / 128) * (CDIM / 128), 256, 0, stream>>>(
      zbuf, w2t, b2, nullptr, out);
}

// Round 2
// 1030.145 us; speedup vs baseline: 1.0098x; 1.0098x over previous
//
#include <hip/hip_runtime.h>
#include <hip/hip_bf16.h>

// SwinMLP block, fp32 in/out, bf16 MFMA internals.
// Pipeline:
//   1) cvt_t: w1 -> w1t (bf16, N x K), w2 -> w2t (bf16, N x K)
//   2) fused_pre: per-row LN1 + per-head 32x32 spatial matmul + residual -> x2 (fp32, stored in d_out)
//      + LN2(x2) -> y (bf16, ws)
//   3) gemm_bt<512,2048,GELU>: z = gelu(y @ w1 + b1)  (bf16, ws)
//   4) gemm_bt<2048,512,RES>:  d_out = x2 + z @ w2 + b2 (in-place residual on d_out)
//
// R2 change: bijective XCD-aware blockIdx swizzle on both GEMMs (T1).
// Mechanism: consecutive logical tiles share an A-panel; default dispatch
// round-robins them across 8 XCD-private L2s -> ~8x A re-fetch from HBM
// (gemm1 FETCH 919 MB vs 105 MB ideal) and HBM-latency stalls at the
// per-K-step barrier. Swizzle gives each XCD a contiguous logical chunk.

typedef __bf16 bf16x8 __attribute__((ext_vector_type(8)));
typedef float f32x4 __attribute__((ext_vector_type(4)));

constexpr int CDIM = 512;
constexpr int HID = 2048;
constexpr int MROWS = 32 * 3136;  // 100352 = 784 * 128
constexpr float LN_EPS = 1e-5f;

static __device__ __forceinline__ float gelu_tanh(float x) {
  // 0.5*x*(1+tanh(sqrt(2/pi)*(x+0.044715 x^3))), tanh via exp (overflow-safe)
  const float u = 0.7978845608028654f * fmaf(0.044715f * x * x, x, x);
  const float e = __expf(2.0f * u);
  return 0.5f * x * (2.0f - 2.0f / (e + 1.0f));
}

static __device__ __forceinline__ void load_lds16(const void* g, void* l) {
  // 16B per lane, LDS dest = wave-uniform base + lane*16 (linear)
  __builtin_amdgcn_global_load_lds((__attribute__((address_space(1))) void*)g,
                                   (__attribute__((address_space(3))) void*)l,
                                   16, 0, 0);
}

// ---------------- weight transpose + bf16 convert ----------------
// dst[n*KD + k] = src[k*ND + n]
template <int KD>
__global__ __launch_bounds__(256) void cvt_t(const float* __restrict__ src,
                                             __hip_bfloat16* __restrict__ dst,
                                             int ND) {
  const int i = blockIdx.x * 256 + threadIdx.x;
  const int n = i / KD;
  const int k = i - n * KD;
  dst[i] = __float2bfloat16(src[(size_t)k * ND + n]);
}

// ---------------- fused LN1 + spatial mix + residual + LN2 ----------------
__global__ __launch_bounds__(256) void fused_pre(
    const float* __restrict__ x, const float* __restrict__ g1,
    const float* __restrict__ b1, const float* __restrict__ wsp,
    const float* __restrict__ g2, const float* __restrict__ b2,
    float* __restrict__ x2out, __hip_bfloat16* __restrict__ yout) {
  __shared__ float lnbuf[CDIM];
  __shared__ float red[8];

  const int t = threadIdx.x;
  const int lane = t & 63;
  const int w = t >> 6;
  const int c0 = t, c1 = t + 256;
  const int hd0 = c0 >> 5, e0 = c0 & 31;
  const int hd1 = c1 >> 5, e1 = c1 & 31;

  // per-thread spatial-mix weight columns (fixed across rows)
  float wc0[32], wc1[32];
#pragma unroll
  for (int d = 0; d < 32; ++d) {
    wc0[d] = wsp[(hd0 * 32 + d) * 32 + e0];
    wc1[d] = wsp[(hd1 * 32 + d) * 32 + e1];
  }
  const float g1v0 = g1[c0], g1v1 = g1[c1], b1v0 = b1[c0], b1v1 = b1[c1];
  const float g2v0 = g2[c0], g2v1 = g2[c1], b2v0 = b2[c0], b2v1 = b2[c1];

  for (int r = blockIdx.x; r < MROWS; r += gridDim.x) {
    const float* xr = x + (size_t)r * CDIM;
    const float xv0 = xr[c0], xv1 = xr[c1];

    // LN1 stats
    float s = xv0 + xv1, ss = xv0 * xv0 + xv1 * xv1;
#pragma unroll
    for (int off = 32; off; off >>= 1) {
      s += __shfl_down(s, off);
      ss += __shfl_down(ss, off);
    }
    if (lane == 0) { red[w * 2] = s; red[w * 2 + 1] = ss; }
    __syncthreads();  // B1
    s = red[0] + red[2] + red[4] + red[6];
    ss = red[1] + red[3] + red[5] + red[7];
    float mu = s * (1.0f / CDIM);
    float var = ss * (1.0f / CDIM) - mu * mu;
    float rs = rsqrtf(var + LN_EPS);
    lnbuf[c0] = (xv0 - mu) * rs * g1v0 + b1v0;
    lnbuf[c1] = (xv1 - mu) * rs * g1v1 + b1v1;
    __syncthreads();  // B2

    // per-head 32x32 matmul (2-way LDS broadcast per wave: conflict-free)
    float h0 = 0.f, h1 = 0.f;
#pragma unroll
    for (int d = 0; d < 32; ++d) {
      h0 = fmaf(lnbuf[hd0 * 32 + d], wc0[d], h0);
      h1 = fmaf(lnbuf[hd1 * 32 + d], wc1[d], h1);
    }
    const float a0 = xv0 + h0, a1 = xv1 + h1;
    x2out[(size_t)r * CDIM + c0] = a0;
    x2out[(size_t)r * CDIM + c1] = a1;

    // LN2 stats
    s = a0 + a1;
    ss = a0 * a0 + a1 * a1;
#pragma unroll
    for (int off = 32; off; off >>= 1) {
      s += __shfl_down(s, off);
      ss += __shfl_down(ss, off);
    }
    if (lane == 0) { red[w * 2] = s; red[w * 2 + 1] = ss; }
    __syncthreads();  // B3
    s = red[0] + red[2] + red[4] + red[6];
    ss = red[1] + red[3] + red[5] + red[7];
    mu = s * (1.0f / CDIM);
    var = ss * (1.0f / CDIM) - mu * mu;
    rs = rsqrtf(var + LN_EPS);
    yout[(size_t)r * CDIM + c0] = __float2bfloat16((a0 - mu) * rs * g2v0 + b2v0);
    yout[(size_t)r * CDIM + c1] = __float2bfloat16((a1 - mu) * rs * g2v1 + b2v1);
    __syncthreads();  // B4 (lnbuf/red reuse next row)
  }
}

// ---------------- bf16 MFMA GEMM: C(MxN) = A(MxK) * Bt(NxK)^T ----------------
// m97 structure: 128x128 tile, 4 waves (2x2 of 64x64), BK=32, global_load_lds w16,
// 2 barriers per K-step. GELU=true: zout=bf16 gelu(acc+bias). else: fout += acc+bias.
// T1: XCD-aware swizzle (grid % 8 == 0 guaranteed by caller).
template <int K, int N, bool GELU>
__global__ __launch_bounds__(256) void gemm_bt(
    const __hip_bfloat16* __restrict__ A, const __hip_bfloat16* __restrict__ Bt,
    const float* __restrict__ bias, __hip_bfloat16* __restrict__ zout,
    float* __restrict__ fout) {
  constexpr int NT = N / 128;
  __shared__ __attribute__((aligned(16))) __hip_bfloat16 As[128 * 32];
  __shared__ __attribute__((aligned(16))) __hip_bfloat16 Bs[128 * 32];

  const int tid = threadIdx.x;
  const int lane = tid & 63;
  const int w = tid >> 6;
  const int wr = w >> 1, wc = w & 1;

  // XCD swizzle: HW assigns blockIdx round-robin to XCDs (xcd = orig % 8).
  // Map so each XCD owns a contiguous logical chunk -> A-panels read once
  // per chip instead of once per XCD, and stay hot in that XCD's L2.
  const int cpx = gridDim.x >> 3;  // grid % 8 == 0
  const int bid = (blockIdx.x & 7) * cpx + (blockIdx.x >> 3);

  const int tm = bid / NT;  // consecutive logical bids share the A panel
  const int tn = bid - tm * NT;
  const size_t am0 = (size_t)tm * 128;
  const int bn0 = tn * 128;

  // staging: segment s in [0,512) of 16B; rows = s>>2, k-sub = (s&3)*8
  const int s0 = w * 64 + lane;
  const int r0 = s0 >> 2, k0 = (s0 & 3) * 8;
  const int s1 = s0 + 256;
  const int r1 = s1 >> 2, k1 = (s1 & 3) * 8;
  const __hip_bfloat16* a0p = A + (am0 + r0) * K + k0;
  const __hip_bfloat16* a1p = A + (am0 + r1) * K + k1;
  const __hip_bfloat16* b0p = Bt + (size_t)(bn0 + r0) * K + k0;
  const __hip_bfloat16* b1p = Bt + (size_t)(bn0 + r1) * K + k1;
  __hip_bfloat16* lA0 = As + (size_t)(w * 64) * 8;
  __hip_bfloat16* lA1 = As + (size_t)(w * 64 + 256) * 8;
  __hip_bfloat16* lB0 = Bs + (size_t)(w * 64) * 8;
  __hip_bfloat16* lB1 = Bs + (size_t)(w * 64 + 256) * 8;

  f32x4 acc[4][4] = {};
  const int fr = lane & 15;
  const int kg = (lane >> 4) * 8;

  for (int kt = 0; kt < K / 32; ++kt) {
    const int kb = kt * 32;
    load_lds16(a0p + kb, lA0);
    load_lds16(a1p + kb, lA1);
    load_lds16(b0p + kb, lB0);
    load_lds16(b1p + kb, lB1);
    __syncthreads();  // drains vmcnt(0) then barrier

    bf16x8 af[4], bfv[4];
#pragma unroll
    for (int m = 0; m < 4; ++m)
      af[m] = *(const bf16x8*)(As + (wr * 64 + m * 16 + fr) * 32 + kg);
#pragma unroll
    for (int n = 0; n < 4; ++n)
      bfv[n] = *(const bf16x8*)(Bs + (wc * 64 + n * 16 + fr) * 32 + kg);
#pragma unroll
    for (int m = 0; m < 4; ++m)
#pragma unroll
      for (int n = 0; n < 4; ++n)
        acc[m][n] = __builtin_amdgcn_mfma_f32_16x16x32_bf16(af[m], bfv[n],
                                                            acc[m][n], 0, 0, 0);
    __syncthreads();  // LDS reads done before next stage
  }

  // epilogue: C/D mapping col = lane&15, row = (lane>>4)*4 + j  [m89/m91-verified]
  const int cr = (lane >> 4) * 4;
  const int cc = lane & 15;
#pragma unroll
  for (int n = 0; n < 4; ++n) {
    const int col = bn0 + wc * 64 + n * 16 + cc;
    const float bv = bias[col];
#pragma unroll
    for (int m = 0; m < 4; ++m) {
      const size_t row = am0 + wr * 64 + m * 16 + cr;
#pragma unroll
      for (int j = 0; j < 4; ++j) {
        const float v = acc[m][n][j] + bv;
        const size_t off = (row + j) * N + col;
        if constexpr (GELU) {
          zout[off] = __float2bfloat16(gelu_tanh(v));
        } else {
          fout[off] = fout[off] + v;  // += x2 residual (in-place on d_out)
        }
      }
    }
  }
}

extern "C" void kernel_launch(void* const* d_in, const int* in_sizes, int n_in,
                              void* d_out, int out_size, void* d_ws,
                              size_t ws_size, hipStream_t stream) {
  const float* x = (const float*)d_in[0];
  const float* n1g = (const float*)d_in[1];
  const float* n1b = (const float*)d_in[2];
  const float* wsp = (const float*)d_in[3];
  const float* n2g = (const float*)d_in[4];
  const float* n2b = (const float*)d_in[5];
  const float* w1 = (const float*)d_in[6];
  const float* b1 = (const float*)d_in[7];
  const float* w2 = (const float*)d_in[8];
  const float* b2 = (const float*)d_in[9];
  float* out = (float*)d_out;

  // ws layout (bf16): y[M*512] | z[M*2048] | w1t[2048*512] | w2t[512*2048]
  // total = 518 MB
  __hip_bfloat16* ybuf = (__hip_bfloat16*)d_ws;
  __hip_bfloat16* zbuf = ybuf + (size_t)MROWS * CDIM;
  __hip_bfloat16* w1t = zbuf + (size_t)MROWS * HID;
  __hip_bfloat16* w2t = w1t + (size_t)CDIM * HID;

  cvt_t<CDIM><<<(CDIM * HID) / 256, 256, 0, stream>>>(w1, w1t, HID);
  cvt_t<HID><<<(CDIM * HID) / 256, 256, 0, stream>>>(w2, w2t, CDIM);
  fused_pre<<<2048, 256, 0, stream>>>(x, n1g, n1b, wsp, n2g, n2b, out, ybuf);
  // grids: 784*16 = 12544 and 784*4 = 3136, both % 8 == 0 (bijective swizzle ok)
  gemm_bt<CDIM, HID, true><<<(MROWS / 128) * (HID / 128), 256, 0, stream>>>(
      ybuf, w1t, b1, zbuf, nullptr);
  gemm_bt<HID, CDIM, false><<<(MROWS / 128) * (CDIM / 128), 256, 0, stream>>>(
      zbuf, w2t, b2, nullptr, out);
}